// Round 1
// baseline (330.603 us; speedup 1.0000x reference)
//
#include <hip/hip_runtime.h>

typedef unsigned short u16;
typedef __attribute__((ext_vector_type(8))) short short8;
typedef __attribute__((ext_vector_type(4))) float f32x4;

#define S_LEN 2048
#define NH 16
#define HD 64
#define DM 1024

__device__ __forceinline__ u16 f2bf(float f) {
    union { float f; unsigned int u; } v; v.f = f;
    unsigned int u = v.u;
    unsigned int r = u + 0x7fffu + ((u >> 16) & 1u);
    return (u16)(r >> 16);
}
__device__ __forceinline__ float bf2f(u16 h) {
    union { unsigned int u; float f; } v; v.u = ((unsigned int)h) << 16;
    return v.f;
}

// ---------------- fp32 -> bf16 convert (flat) ----------------
__global__ __launch_bounds__(256) void cvt_bf16(const float* __restrict__ in, u16* __restrict__ out, int n) {
    int i = (blockIdx.x * 256 + threadIdx.x) * 4;
    if (i < n) {
        float4 v = *(const float4*)(in + i);
        ushort4 o;
        o.x = f2bf(v.x); o.y = f2bf(v.y); o.z = f2bf(v.z); o.w = f2bf(v.w);
        *(ushort4*)(out + i) = o;
    }
}

// ---------------- W [K][N] fp32 -> Wt [N][K] bf16 ----------------
__global__ __launch_bounds__(256) void transpose_w(const float* __restrict__ W, u16* __restrict__ Wt) {
    __shared__ float tile[32][33];
    int tx = threadIdx.x, ty = threadIdx.y;           // 32 x 8
    int k0 = blockIdx.y * 32, n0 = blockIdx.x * 32;
    #pragma unroll
    for (int j = 0; j < 32; j += 8)
        tile[ty + j][tx] = W[(size_t)(k0 + ty + j) * DM + n0 + tx];
    __syncthreads();
    #pragma unroll
    for (int j = 0; j < 32; j += 8)
        Wt[(size_t)(n0 + ty + j) * DM + k0 + tx] = f2bf(tile[tx][ty + j]);
}

// ---------------- GEMM: C[m][n] = sum_k A[m][k]*Bt[n][k] ----------------
// MODE 0: fp32 flat [M][N]
// MODE 1: bf16 head-major [B][H][S][HD]   (for Q, K)
// MODE 2: bf16 V-transposed [B][H][HD][S] (for V)
template<int MODE>
__global__ __launch_bounds__(256) void gemm_bt(const u16* __restrict__ A, const u16* __restrict__ Bt,
                                               void* __restrict__ outp, int M, int N, int K) {
    __shared__ u16 Al[64][40];
    __shared__ u16 Bl[64][40];
    int tid = threadIdx.x;
    int wave = tid >> 6, lane = tid & 63, g = lane >> 4, ln = lane & 15;
    int wm = (wave >> 1) * 32, wn = (wave & 1) * 32;
    int m0 = blockIdx.y * 64, n0 = blockIdx.x * 64;
    f32x4 acc[2][2] = {{{0.f,0.f,0.f,0.f},{0.f,0.f,0.f,0.f}},{{0.f,0.f,0.f,0.f},{0.f,0.f,0.f,0.f}}};
    int srow = tid >> 2, sc8 = (tid & 3) * 8;
    for (int k0 = 0; k0 < K; k0 += 32) {
        __syncthreads();
        *(short8*)&Al[srow][sc8] = *(const short8*)(A + (size_t)(m0 + srow) * K + k0 + sc8);
        *(short8*)&Bl[srow][sc8] = *(const short8*)(Bt + (size_t)(n0 + srow) * K + k0 + sc8);
        __syncthreads();
        short8 a0 = *(const short8*)&Al[wm + ln][g * 8];
        short8 a1 = *(const short8*)&Al[wm + 16 + ln][g * 8];
        short8 b0 = *(const short8*)&Bl[wn + ln][g * 8];
        short8 b1 = *(const short8*)&Bl[wn + 16 + ln][g * 8];
        acc[0][0] = __builtin_amdgcn_mfma_f32_16x16x32_bf16(a0, b0, acc[0][0], 0, 0, 0);
        acc[0][1] = __builtin_amdgcn_mfma_f32_16x16x32_bf16(a0, b1, acc[0][1], 0, 0, 0);
        acc[1][0] = __builtin_amdgcn_mfma_f32_16x16x32_bf16(a1, b0, acc[1][0], 0, 0, 0);
        acc[1][1] = __builtin_amdgcn_mfma_f32_16x16x32_bf16(a1, b1, acc[1][1], 0, 0, 0);
    }
    #pragma unroll
    for (int mi = 0; mi < 2; mi++)
    #pragma unroll
    for (int ni = 0; ni < 2; ni++)
    #pragma unroll
    for (int r = 0; r < 4; r++) {
        int m = m0 + wm + mi * 16 + g * 4 + r;
        int n = n0 + wn + ni * 16 + ln;
        float v = acc[mi][ni][r];
        if (MODE == 0) {
            ((float*)outp)[(size_t)m * N + n] = v;
        } else {
            u16 hv = f2bf(v);
            int b = m >> 11, s = m & (S_LEN - 1);
            int hh = n >> 6, d = n & (HD - 1);
            if (MODE == 1)
                ((u16*)outp)[(((size_t)(b * NH + hh) * S_LEN + s) * HD + d)] = hv;
            else
                ((u16*)outp)[(((size_t)(b * NH + hh) * HD + d) * S_LEN + s)] = hv;
        }
    }
}

// ---------------- RoPE in-place on [BH][S][HD] bf16 ----------------
__global__ __launch_bounds__(256) void rope_kernel(u16* __restrict__ T) {
    int idx = blockIdx.x * 256 + threadIdx.x;   // < 32*2048*32
    int i = idx & 31;
    int s = (idx >> 5) & (S_LEN - 1);
    int bh = idx >> 16;
    size_t base = ((size_t)bh * S_LEN + s) * HD;
    float t1 = bf2f(T[base + i]), t2 = bf2f(T[base + 32 + i]);
    float inv_freq = __powf(10000.0f, -(float)(2 * i) / 64.0f);
    float fr = (float)s * inv_freq;
    float c = __cosf(fr), sn = __sinf(fr);
    T[base + i]      = f2bf(t1 * c - t2 * sn);
    T[base + 32 + i] = f2bf(t1 * sn + t2 * c);
}

// ---------------- Flash attention (causal, online softmax) ----------------
// Qh,Kh: [BH][S][HD] bf16 (rope'd), Vt: [BH][HD][S] bf16, amask: [B][S] fp32
// attn out: [B][S][DM] bf16
__global__ __launch_bounds__(256) void flash_kernel(const u16* __restrict__ Qh, const u16* __restrict__ Kh,
                                                    const u16* __restrict__ Vt, const float* __restrict__ amask,
                                                    u16* __restrict__ attn) {
    __shared__ u16 Kl[64][72];
    __shared__ u16 Vl[64][72];
    __shared__ u16 Pl[64][72];
    __shared__ float Ml[64];
    int tid = threadIdx.x;
    int wave = tid >> 6, lane = tid & 63, g = lane >> 4, ln = lane & 15;
    int qtile = blockIdx.x, bh = blockIdx.y;
    int b = bh / NH, h = bh % NH;
    int qbase = qtile * 64;
    const u16* Qb = Qh + (size_t)bh * S_LEN * HD;
    const u16* Kb = Kh + (size_t)bh * S_LEN * HD;
    const u16* Vb = Vt + (size_t)bh * HD * S_LEN;

    int qm = qbase + wave * 16 + ln;
    short8 qa0 = *(const short8*)(Qb + (size_t)qm * HD + g * 8);
    short8 qa1 = *(const short8*)(Qb + (size_t)qm * HD + 32 + g * 8);

    f32x4 O[4] = {{0.f,0.f,0.f,0.f},{0.f,0.f,0.f,0.f},{0.f,0.f,0.f,0.f},{0.f,0.f,0.f,0.f}};
    float m_run[4], l_run[4];
    #pragma unroll
    for (int r = 0; r < 4; r++) { m_run[r] = -1e30f; l_run[r] = 0.f; }
    const float scale = 0.125f;

    for (int kt = 0; kt <= qtile; ++kt) {
        int kbase = kt * 64;
        __syncthreads();
        #pragma unroll
        for (int p = 0; p < 2; p++) {
            int idx = tid + p * 256;
            int row = idx >> 3, c8 = (idx & 7) * 8;
            *(short8*)&Kl[row][c8] = *(const short8*)(Kb + (size_t)(kbase + row) * HD + c8);
            *(short8*)&Vl[row][c8] = *(const short8*)(Vb + (size_t)row * S_LEN + kbase + c8);
        }
        if (tid < 64) Ml[tid] = (1.0f - amask[b * S_LEN + kbase + tid]) * -1e9f;
        __syncthreads();

        // scores: 16 q-rows x 64 keys per wave
        float sarr[4][4];
        #pragma unroll
        for (int n0 = 0; n0 < 4; n0++) {
            short8 kb0 = *(const short8*)&Kl[n0 * 16 + ln][g * 8];
            short8 kb1 = *(const short8*)&Kl[n0 * 16 + ln][32 + g * 8];
            f32x4 sv = {0.f, 0.f, 0.f, 0.f};
            sv = __builtin_amdgcn_mfma_f32_16x16x32_bf16(qa0, kb0, sv, 0, 0, 0);
            sv = __builtin_amdgcn_mfma_f32_16x16x32_bf16(qa1, kb1, sv, 0, 0, 0);
            float mk = Ml[n0 * 16 + ln];
            int key = kbase + n0 * 16 + ln;
            #pragma unroll
            for (int r = 0; r < 4; r++) {
                int q = qbase + wave * 16 + g * 4 + r;
                sarr[n0][r] = sv[r] * scale + mk + ((key > q) ? -1e9f : 0.f);
            }
        }
        // row max across 16 lanes of each group
        float mt[4], lt[4];
        #pragma unroll
        for (int r = 0; r < 4; r++) {
            float m = fmaxf(fmaxf(sarr[0][r], sarr[1][r]), fmaxf(sarr[2][r], sarr[3][r]));
            mt[r] = m;
        }
        #pragma unroll
        for (int d = 1; d < 16; d <<= 1)
            #pragma unroll
            for (int r = 0; r < 4; r++) mt[r] = fmaxf(mt[r], __shfl_xor(mt[r], d, 64));
        float alpha[4];
        #pragma unroll
        for (int r = 0; r < 4; r++) {
            float mn = fmaxf(m_run[r], mt[r]);
            alpha[r] = __expf(m_run[r] - mn);
            m_run[r] = mn;
            lt[r] = 0.f;
        }
        #pragma unroll
        for (int n0 = 0; n0 < 4; n0++)
            #pragma unroll
            for (int r = 0; r < 4; r++) {
                float p = __expf(sarr[n0][r] - m_run[r]);
                sarr[n0][r] = p;
                lt[r] += p;
            }
        #pragma unroll
        for (int d = 1; d < 16; d <<= 1)
            #pragma unroll
            for (int r = 0; r < 4; r++) lt[r] += __shfl_xor(lt[r], d, 64);
        #pragma unroll
        for (int r = 0; r < 4; r++) l_run[r] = l_run[r] * alpha[r] + lt[r];
        #pragma unroll
        for (int n0 = 0; n0 < 4; n0++)
            #pragma unroll
            for (int r = 0; r < 4; r++) O[n0][r] *= alpha[r];

        // P (C-layout) -> LDS -> A-layout
        #pragma unroll
        for (int n0 = 0; n0 < 4; n0++)
            #pragma unroll
            for (int r = 0; r < 4; r++)
                Pl[wave * 16 + g * 4 + r][n0 * 16 + ln] = f2bf(sarr[n0][r]);
        __syncthreads();
        short8 pa0 = *(const short8*)&Pl[wave * 16 + ln][g * 8];
        short8 pa1 = *(const short8*)&Pl[wave * 16 + ln][32 + g * 8];
        #pragma unroll
        for (int n0 = 0; n0 < 4; n0++) {
            short8 vb0 = *(const short8*)&Vl[n0 * 16 + ln][g * 8];
            short8 vb1 = *(const short8*)&Vl[n0 * 16 + ln][32 + g * 8];
            O[n0] = __builtin_amdgcn_mfma_f32_16x16x32_bf16(pa0, vb0, O[n0], 0, 0, 0);
            O[n0] = __builtin_amdgcn_mfma_f32_16x16x32_bf16(pa1, vb1, O[n0], 0, 0, 0);
        }
    }
    // epilogue: normalize, store bf16 to [B][S][DM]
    #pragma unroll
    for (int r = 0; r < 4; r++) {
        float inv = 1.0f / l_run[r];
        int q = qbase + wave * 16 + g * 4 + r;
        size_t base = ((size_t)b * S_LEN + q) * DM + h * HD;
        #pragma unroll
        for (int n0 = 0; n0 < 4; n0++)
            attn[base + n0 * 16 + ln] = f2bf(O[n0][r] * inv);
    }
}

extern "C" void kernel_launch(void* const* d_in, const int* in_sizes, int n_in,
                              void* d_out, int out_size, void* d_ws, size_t ws_size,
                              hipStream_t stream) {
    const float* x     = (const float*)d_in[0];
    const float* amask = (const float*)d_in[1];
    const float* Wq    = (const float*)d_in[2];
    const float* Wk    = (const float*)d_in[3];
    const float* Wv    = (const float*)d_in[4];
    const float* Wo    = (const float*)d_in[5];
    float* out = (float*)d_out;
    char* ws = (char*)d_ws;

    u16* x_bf = (u16*)(ws);                        // 8 MB
    u16* Wq_t = (u16*)(ws + 8388608);              // 2 MB
    u16* Wk_t = (u16*)(ws + 10485760);             // 2 MB
    u16* Wv_t = (u16*)(ws + 12582912);             // 2 MB
    u16* Wo_t = (u16*)(ws + 14680064);             // 2 MB
    u16* Qh   = (u16*)(ws + 16777216);             // 8 MB
    u16* Kh   = (u16*)(ws + 25165824);             // 8 MB
    u16* Vt   = (u16*)(ws + 33554432);             // 8 MB
    u16* attn = (u16*)(ws + 41943040);             // 8 MB

    cvt_bf16<<<4096, 256, 0, stream>>>(x, x_bf, 2 * S_LEN * DM);

    dim3 tb(32, 8), tg(32, 32);
    transpose_w<<<tg, tb, 0, stream>>>(Wq, Wq_t);
    transpose_w<<<tg, tb, 0, stream>>>(Wk, Wk_t);
    transpose_w<<<tg, tb, 0, stream>>>(Wv, Wv_t);
    transpose_w<<<tg, tb, 0, stream>>>(Wo, Wo_t);

    dim3 gg(DM / 64, (2 * S_LEN) / 64);            // (16, 64)
    gemm_bt<1><<<gg, 256, 0, stream>>>(x_bf, Wq_t, Qh, 2 * S_LEN, DM, DM);
    gemm_bt<1><<<gg, 256, 0, stream>>>(x_bf, Wk_t, Kh, 2 * S_LEN, DM, DM);
    gemm_bt<2><<<gg, 256, 0, stream>>>(x_bf, Wv_t, Vt, 2 * S_LEN, DM, DM);

    rope_kernel<<<8192, 256, 0, stream>>>(Qh);
    rope_kernel<<<8192, 256, 0, stream>>>(Kh);

    flash_kernel<<<dim3(S_LEN / 64, 2 * NH), 256, 0, stream>>>(Qh, Kh, Vt, amask, attn);

    gemm_bt<0><<<gg, 256, 0, stream>>>(attn, Wo_t, out, 2 * S_LEN, DM, DM);
}